// Round 1
// baseline (234.303 us; speedup 1.0000x reference)
//
#include <hip/hip_runtime.h>

// Fused 5-iteration Jacobi, cross-stencil, B=16, H=W=1024 fp32.
// R5: in-place sweeps. Each thread reads its full input set (8 row-float4s +
// 4 halo float2 pairs) into registers BEFORE computing, so the ping-pong
// double buffer is unnecessary: read-to-regs -> barrier -> write-in-place ->
// barrier is exact Jacobi. LDS drops 64 KiB -> 32 KiB per block, lifting
// residency from 2 to 4 blocks/CU (32 waves = HW cap) to hide ds_read
// latency and barrier bubbles (previous version: occupancy 41%, all pipes
// <50% busy -> latency-bound).
// Geometry unchanged (R4): row = 128 floats, stride % 32 banks == 0, b128
// phases conflict-free. Tile 128x64, output 104x40/block, grid 10x26x16,
// 5 sweeps, full-region recompute, EDGE mask only on ring blocks.

#define HH 1024
#define WW 1024
#define NB 16
#define TX 104
#define TY 40
#define HALO 12
#define TWX 128            // LDS row width == stride (floats)
#define TWY 64             // TY + 2*HALO
#define NGX 32             // float4 groups per row
#define NITER 5
#define NTHREADS 512
#define NQ 15              // row quads covering rows [2,62)
#define NITEMS (NQ * NGX)  // 480

struct Coef { float sH1, sH2, sW1, sW2; };

template <bool EDGE>
__device__ __forceinline__ float4 upd_row(
    const float4 a2, const float4 a1, const float4 ct, const float4 b1, const float4 b2,
    const float2 hm, const float2 hp, const float4 rv, const Coef cf,
    const int gy, const int gx0)
{
    const float A2[4] = {a2.x, a2.y, a2.z, a2.w};
    const float A1[4] = {a1.x, a1.y, a1.z, a1.w};
    const float CT[4] = {ct.x, ct.y, ct.z, ct.w};
    const float B1[4] = {b1.x, b1.y, b1.z, b1.w};
    const float B2[4] = {b2.x, b2.y, b2.z, b2.w};
    const float RV[4] = {rv.x, rv.y, rv.z, rv.w};
    const float cc[8] = {hm.x, hm.y, ct.x, ct.y, ct.z, ct.w, hp.x, hp.y};
    const bool rowok = (gy >= 2) && (gy < HH - 2);
    float o[4];
#pragma unroll
    for (int k = 0; k < 4; ++k) {
        float v = RV[k];
        v = fmaf(cf.sH2, A2[k] + B2[k], v);
        v = fmaf(cf.sH1, A1[k] + B1[k], v);
        v = fmaf(cf.sW2, cc[k] + cc[k + 4], v);
        v = fmaf(cf.sW1, cc[k + 1] + cc[k + 3], v);
        if (EDGE) {
            const int gx = gx0 + k;
            const bool ok = rowok && (gx >= 2) && (gx < WW - 2);
            v = ok ? v : CT[k];
        }
        o[k] = v;
    }
    return make_float4(o[0], o[1], o[2], o[3]);
}

template <bool EDGE>
__device__ __forceinline__ void do_sweeps(
    float* buf, const bool active, const int r, const int c,
    const int gx0, const int gy0, const float4* rv, const Coef cf)
{
    float* s = buf + r * TWX + c;
#pragma unroll
    for (int it = 0; it < NITER; ++it) {
        float4 o0, o1, o2, o3;
        if (active) {
            const float4 f0 = *(const float4*)(s - 2 * TWX);
            const float4 f1 = *(const float4*)(s - 1 * TWX);
            const float4 f2 = *(const float4*)(s);
            const float4 f3 = *(const float4*)(s + 1 * TWX);
            const float4 f4 = *(const float4*)(s + 2 * TWX);
            const float4 f5 = *(const float4*)(s + 3 * TWX);
            const float4 f6 = *(const float4*)(s + 4 * TWX);
            const float4 f7 = *(const float4*)(s + 5 * TWX);
            const float2 h0m = *(const float2*)(s - 2);
            const float2 h0p = *(const float2*)(s + 4);
            const float2 h1m = *(const float2*)(s + TWX - 2);
            const float2 h1p = *(const float2*)(s + TWX + 4);
            const float2 h2m = *(const float2*)(s + 2 * TWX - 2);
            const float2 h2p = *(const float2*)(s + 2 * TWX + 4);
            const float2 h3m = *(const float2*)(s + 3 * TWX - 2);
            const float2 h3p = *(const float2*)(s + 3 * TWX + 4);

            o0 = upd_row<EDGE>(f0, f1, f2, f3, f4, h0m, h0p, rv[0], cf, gy0 + 0, gx0);
            o1 = upd_row<EDGE>(f1, f2, f3, f4, f5, h1m, h1p, rv[1], cf, gy0 + 1, gx0);
            o2 = upd_row<EDGE>(f2, f3, f4, f5, f6, h2m, h2p, rv[2], cf, gy0 + 2, gx0);
            o3 = upd_row<EDGE>(f3, f4, f5, f6, f7, h3m, h3p, rv[3], cf, gy0 + 3, gx0);
        }
        __syncthreads();   // all reads of iteration `it` retired
        if (active) {
            *(float4*)(s)           = o0;
            *(float4*)(s + 1 * TWX) = o1;
            *(float4*)(s + 2 * TWX) = o2;
            *(float4*)(s + 3 * TWX) = o3;
        }
        __syncthreads();   // all writes visible before next read phase
    }
}

__global__ __launch_bounds__(NTHREADS, 8) void jacobi_fused(
    const float* __restrict__ g0, const float* __restrict__ rhs,
    const float* __restrict__ dx, float* __restrict__ out)
{
    __shared__ __align__(16) float buf[TWY * TWX];   // 32 KiB -> 4 blocks/CU

    const int tid = (int)threadIdx.x;
    const int tx = (int)blockIdx.x, ty = (int)blockIdx.y, b = (int)blockIdx.z;
    const int x0 = tx * TX, y0 = ty * TY;

    const float* gb = g0 + (size_t)b * HH * WW;
    const float* rb = rhs + (size_t)b * HH * WW;
    float* ob = out + (size_t)b * HH * WW;

    // per-batch coefficients (d_inv and the -cr sign folded in)
    const float t0 = 1.0f / dx[2 * b + 0], t1 = 1.0f / dx[2 * b + 1];
    const float p0 = t0 * t0, p1 = t1 * t1;
    const float d_inv = 1.0f / (-2.5f * (p0 + p1));
    Coef cf;
    cf.sH1 = -d_inv * (4.0f / 3.0f) * p0;
    cf.sH2 = -d_inv * (-1.0f / 12.0f) * p0;
    cf.sW1 = -d_inv * (4.0f / 3.0f) * p1;
    cf.sW2 = -d_inv * (-1.0f / 12.0f) * p1;

    // ---- fixed work item: 4 rows x 4 cols; lane%32 == col group -> b128 phases
    //      are 32-bank aligned ----
    const bool active = tid < NITEMS;
    const int q = tid >> 5;            // row quad 0..14
    const int cg = tid & 31;           // col group 0..31
    const int r = 2 + 4 * q;           // rows r..r+3 in [2,62)
    const int c = 4 * cg;              // cols c..c+3 in [0,128)
    const int gx0 = x0 - HALO + c;
    const int gy0 = y0 - HALO + r;

    // rhs * d_inv preload (clamped; clamped lanes only feed masked/garbage points)
    float4 rv[4] = {};
    if (active) {
        int gxc = gx0 < 0 ? 0 : (gx0 > WW - 4 ? WW - 4 : gx0);
#pragma unroll
        for (int j = 0; j < 4; ++j) {
            int gy = gy0 + j;
            gy = gy < 0 ? 0 : (gy > HH - 1 ? HH - 1 : gy);
            float4 v = *(const float4*)(rb + (size_t)gy * WW + gxc);
            rv[j] = make_float4(d_inv * v.x, d_inv * v.y, d_inv * v.z, d_inv * v.w);
        }
    }

    // ---- load 128x64 input tile into buf (clamp-replicate at domain edges) ----
#pragma unroll
    for (int tt = 0; tt < (TWY * NGX) / NTHREADS; ++tt) {
        const int t = tid + tt * NTHREADS;
        const int ly = t >> 5;
        const int c4 = (t & 31) * 4;
        int gy = y0 - HALO + ly;
        gy = gy < 0 ? 0 : (gy > HH - 1 ? HH - 1 : gy);
        const int gxl = x0 - HALO + c4;
        const float* row = gb + (size_t)gy * WW;
        float4 v;
        if (gxl >= 0 && gxl <= WW - 4) {
            v = *(const float4*)(row + gxl);
        } else {
            int xa = gxl + 0; xa = xa < 0 ? 0 : (xa > WW - 1 ? WW - 1 : xa);
            int xb = gxl + 1; xb = xb < 0 ? 0 : (xb > WW - 1 ? WW - 1 : xb);
            int xc = gxl + 2; xc = xc < 0 ? 0 : (xc > WW - 1 ? WW - 1 : xc);
            int xd = gxl + 3; xd = xd < 0 ? 0 : (xd > WW - 1 ? WW - 1 : xd);
            v = make_float4(row[xa], row[xb], row[xc], row[xd]);
        }
        *(float4*)(&buf[ly * TWX + c4]) = v;
    }
    __syncthreads();

    // interior fast path (conservative: dependency cone of the stored center
    // strictly inside the frozen ring)
    const bool interior = (x0 - HALO >= 2) && (x0 + TX + HALO <= WW - 2) &&
                          (y0 - HALO >= 2) && (y0 + TY + HALO <= HH - 2);
    if (interior) do_sweeps<false>(buf, active, r, c, gx0, gy0, rv, cf);
    else          do_sweeps<true >(buf, active, r, c, gx0, gy0, rv, cf);

    // ---- store center: LDS cols [12,116) rows [12,52) -> global 104x40
    //      (guarded for ragged right/bottom tiles); in-place -> data in buf ----
    for (int t = tid; t < TY * (TX / 4); t += NTHREADS) {
        const int rr = t / (TX / 4);
        const int k4 = (t - rr * (TX / 4)) * 4;
        const int gx = x0 + k4;
        const int gy = y0 + rr;
        if (gy < HH && gx <= WW - 4) {
            const float4 v = *(const float4*)(&buf[(HALO + rr) * TWX + HALO + k4]);
            *(float4*)(ob + (size_t)gy * WW + gx) = v;
        }
    }
}

extern "C" void kernel_launch(void* const* d_in, const int* in_sizes, int n_in,
                              void* d_out, int out_size, void* d_ws, size_t ws_size,
                              hipStream_t stream) {
    const float* g0  = (const float*)d_in[0];
    const float* rhs = (const float*)d_in[1];
    const float* dx  = (const float*)d_in[2];
    float* out = (float*)d_out;

    dim3 grid((WW + TX - 1) / TX, (HH + TY - 1) / TY, NB), block(NTHREADS);
    jacobi_fused<<<grid, block, 0, stream>>>(g0, rhs, dx, out);
}